// Round 6
// baseline (566.112 us; speedup 1.0000x reference)
//
#include <hip/hip_runtime.h>
#include <hip/hip_bf16.h>
#include <math.h>

#define NN 100000
#define NE 3200000
#define NF 512
#define NTILE 6250    // NN/16 exactly
#define NB 782        // 128-node buckets per key (782*128 = 100096 >= NN)
#define NB2 1564      // both keys
#define NCH 256       // edge chunks
#define CHUNK 12500   // NE/NCH exactly
#define BCAP 8192     // fixed bucket capacity (mean 4093, ~64 sigma margin)
#define NGB 1563      // gemm1 blocks = ceil(NTILE/4)
#define GBLK 2048     // gather blocks
#define NGRP (GBLK * 16)  // gather 16-lane groups (4 per wave)
#define DONE_IDX 1564     // 'done' counter lives in gcount pad

typedef __attribute__((ext_vector_type(8))) short short8;
typedef __attribute__((ext_vector_type(4))) float f32x4;

__device__ inline unsigned bf16_rne(float f) {
    unsigned u = __builtin_bit_cast(unsigned, f);
    return (u + 0x7FFFu + ((u >> 16) & 1u)) >> 16;
}
__device__ inline float bf16_back(unsigned h) {
    return __builtin_bit_cast(float, h << 16);
}

// ---------------- zero reservation counters + done flag ----------------
__global__ __launch_bounds__(1024) void k_zero(int* __restrict__ gcount) {
    for (int i = threadIdx.x; i < 1600; i += 1024) gcount[i] = 0;
}

// -------- fused hist + place, fixed-capacity buckets (no global scan) ---------
// bucket k segment: packed[k*BCAP .. k*BCAP + gcount[k])
// k = dst>>7 for dst-key copy (payload ((dst&127)<<17)|src)
// k = NB + (src>>7) for src-key copy (payload ((src&127)<<17)|dst)
__global__ __launch_bounds__(256) void k_histplace(const int* __restrict__ src,
                                                   const int* __restrict__ dst,
                                                   int* __restrict__ gcount,
                                                   unsigned* __restrict__ packed) {
    __shared__ int lcnt[NB2];
    __shared__ int sbase[NB2];
    for (int i = threadIdx.x; i < NB2; i += 256) lcnt[i] = 0;
    __syncthreads();
    const int e0 = blockIdx.x * CHUNK;
    // pass 1: count
    for (int i = threadIdx.x; i < CHUNK; i += 256) {
        atomicAdd(&lcnt[dst[e0 + i] >> 7], 1);
        atomicAdd(&lcnt[NB + (src[e0 + i] >> 7)], 1);
    }
    __syncthreads();
    // reserve: rotate start bucket per block to spread same-address contention
    const int rot = (blockIdx.x * 61) % NB2;
    for (int k = threadIdx.x; k < NB2; k += 256) {
        int b = k + rot;
        if (b >= NB2) b -= NB2;
        int c = lcnt[b];
        sbase[b] = b * BCAP + atomicAdd(&gcount[b], c);
        lcnt[b] = 0;  // reuse as cursor
    }
    __syncthreads();
    // pass 2: place (chunk is L2-hot from pass 1)
    for (int i = threadIdx.x; i < CHUNK; i += 256) {
        int d = dst[e0 + i];
        int s = src[e0 + i];
        int bd = d >> 7;
        int pd = atomicAdd(&lcnt[bd], 1);
        packed[sbase[bd] + pd] = ((unsigned)(d & 127) << 17) | (unsigned)s;
        int bs = NB + (s >> 7);
        int ps = atomicAdd(&lcnt[bs], 1);
        packed[sbase[bs] + ps] = ((unsigned)(s & 127) << 17) | (unsigned)d;
    }
}

// ---------------- per-bucket counting sort -> node CSR (+dinv), in place ------
// writes row_start[n], row_end[n] (no sentinel needed), dinv[n]
__global__ __launch_bounds__(256) void k_bsort(unsigned* __restrict__ packed,
                                               const int* __restrict__ gcount,
                                               int* __restrict__ row_start,
                                               int* __restrict__ row_end,
                                               float* __restrict__ dinv) {
    __shared__ unsigned stage[BCAP];
    __shared__ int cnt[128];
    __shared__ int t0[128], t1[128];
    const int tid = threadIdx.x;
    const int b = blockIdx.x;
    const int beg = b * BCAP;
    const int sz = gcount[b];
    if (tid < 128) cnt[tid] = 0;
    __syncthreads();
    for (int i = tid; i < sz; i += 256) {
        unsigned p = packed[beg + i];
        if (i < BCAP) stage[i] = p;
        atomicAdd(&cnt[p >> 17], 1);
    }
    __syncthreads();
    // inclusive Hillis-Steele scan over 128 counts
    if (tid < 128) t0[tid] = cnt[tid];
    __syncthreads();
    int pp = 0;
    for (int off = 1; off < 128; off <<= 1) {
        if (tid < 128) {
            int t = (pp ? t1[tid] : t0[tid]);
            if (tid >= off) t += (pp ? t1[tid - off] : t0[tid - off]);
            if (pp) t0[tid] = t; else t1[tid] = t;
        }
        __syncthreads();
        pp = 1 - pp;
    }
    if (tid < 128) {
        int incl = pp ? t1[tid] : t0[tid];
        int excl = incl - cnt[tid];
        int n = b * 128 + tid;
        if (n < NN) {
            row_start[n] = beg + excl;
            row_end[n] = beg + incl;
            dinv[n] = rsqrtf((float)cnt[tid] + 1.0f);
        }
        cnt[tid] = excl;  // reuse as cursor
    }
    __syncthreads();
    for (int i = tid; i < sz; i += 256) {
        unsigned p = (i < BCAP) ? stage[i] : packed[beg + i];
        int k = p >> 17;
        int pos = atomicAdd(&cnt[k], 1);
        packed[beg + pos] = p & 0x1FFFFu;
    }
}

// ---------------- GEMM1 (MFMA bf16 hi/lo) + csum, disjoint block ranges -------
// blocks [0,NGB): hs[n][c] = dinv[n]*(x@W1)[n][c]
// blocks [NGB,NGB+NB): cacc[s] = sum_{edges s->d} dinv[d]  (latency-bound;
//   co-runs with the HBM-bound gemm -> complementary pipes)
__global__ __launch_bounds__(256) void k_gemm1csum(
    const float* __restrict__ x, const float* __restrict__ W1,
    const float* __restrict__ dinv, float* __restrict__ hs,
    const unsigned* __restrict__ packed, const int* __restrict__ gcount,
    float* __restrict__ cacc) {
    if (blockIdx.x >= NGB) {
        // ---- csum branch ----
        __shared__ float sums[128];
        const int tid = threadIdx.x;
        const int b = blockIdx.x - NGB;
        if (tid < 128) sums[tid] = 0.0f;
        __syncthreads();
        const int beg = (NB + b) * BCAP;
        const int sz = gcount[NB + b];
        for (int i = tid; i < sz; i += 256) {
            unsigned p = packed[beg + i];
            atomicAdd(&sums[p >> 17], dinv[p & 0x1FFFFu]);
        }
        __syncthreads();
        const int n = b * 128 + tid;
        if (tid < 128 && n < NN) cacc[n] = sums[tid];
        return;
    }
    // ---- gemm branch ----
    __shared__ short8 Bh[1024];  // idx = (kk*4+q)*16 + c
    __shared__ short8 Bl[1024];

    const int t = threadIdx.x;
    {   // stage W: thread (c,q,kk0) handles kk = kk0*4+i
        const int c = t & 15, q = (t >> 4) & 3, kk0 = t >> 6;
        for (int i = 0; i < 4; ++i) {
            const int kk = kk0 * 4 + i;
            short8 hi, lo;
#pragma unroll
            for (int j = 0; j < 8; ++j) {
                float w = W1[(kk * 32 + q * 8 + j) * 16 + c];
                unsigned h = bf16_rne(w);
                float back = bf16_back(h);
                unsigned l = bf16_rne(w - back);
                hi[j] = (short)h;
                lo[j] = (short)l;
            }
            Bh[(kk * 4 + q) * 16 + c] = hi;
            Bl[(kk * 4 + q) * 16 + c] = lo;
        }
    }
    __syncthreads();

    const int lane = t & 63;
    const int wave = blockIdx.x * 4 + (t >> 6);
    if (wave >= NTILE) return;
    const int nb = wave * 16;
    const int m = lane & 15;  // A row within tile AND B/C col (channel)
    const int q = lane >> 4;

    const float4* xrow = (const float4*)(x + (size_t)(nb + m) * NF + q * 8);
    float4 xr[32];
#pragma unroll
    for (int kk = 0; kk < 16; ++kk) {
        xr[2 * kk] = xrow[kk * 8];
        xr[2 * kk + 1] = xrow[kk * 8 + 1];
    }

    f32x4 acc = {0.f, 0.f, 0.f, 0.f};
#pragma unroll
    for (int kk = 0; kk < 16; ++kk) {
        float f[8] = {xr[2 * kk].x,     xr[2 * kk].y,     xr[2 * kk].z,
                      xr[2 * kk].w,     xr[2 * kk + 1].x, xr[2 * kk + 1].y,
                      xr[2 * kk + 1].z, xr[2 * kk + 1].w};
        short8 ah, al;
#pragma unroll
        for (int j = 0; j < 8; ++j) {
            unsigned h = bf16_rne(f[j]);
            ah[j] = (short)h;
            al[j] = (short)bf16_rne(f[j] - bf16_back(h));
        }
        short8 bh = Bh[(kk * 4 + q) * 16 + m];
        short8 bl = Bl[(kk * 4 + q) * 16 + m];
        acc = __builtin_amdgcn_mfma_f32_16x16x32_bf16(ah, bh, acc, 0, 0, 0);
        acc = __builtin_amdgcn_mfma_f32_16x16x32_bf16(ah, bl, acc, 0, 0, 0);
        acc = __builtin_amdgcn_mfma_f32_16x16x32_bf16(al, bh, acc, 0, 0, 0);
    }

    // C/D: col=lane&15, row=q*4+reg
#pragma unroll
    for (int r = 0; r < 4; ++r) {
        const int n = nb + q * 4 + r;
        hs[n * 16 + m] = dinv[n] * acc[r];
    }
}

// -------- gather + fused layer-2 finalize/pool + last-block softmax -----------
// 16-lane group per node (4 nodes/wave): slot e=(lane>>2)&3, quad q=lane&3.
// per node: a1 = dinv[n]*(sum_{s in N(n)} hs[s] + hs[n]);
//   pooled partial += w[n]*relu(a1+b1), w[n] = dinv[n]*(cacc[n]+dinv[n]).
// Block partial -> pblock; last block reduces + (t@W2)/N + b2 + softmax -> out.
__global__ __launch_bounds__(256) void k_gather(
    const float* __restrict__ hs, const float* __restrict__ dinv,
    const int* __restrict__ row_start, const int* __restrict__ row_end,
    const unsigned* __restrict__ packed, const float* __restrict__ cacc,
    const float* __restrict__ b1, float* __restrict__ pblock,
    int* __restrict__ done, const float* __restrict__ W2,
    const float* __restrict__ b2, float* __restrict__ out) {
    const int* csr = (const int*)packed;
    const int tid = threadIdx.x;
    const int lane = tid & 63;
    const int wid = tid >> 6;
    const int g2 = lane >> 4;       // group within wave 0..3
    const int e = (lane >> 2) & 3;  // edge slot 0..3
    const int q = lane & 3;         // channel quad 0..3
    const int grp = blockIdx.x * 16 + wid * 4 + g2;
    const float4 b1v = ((const float4*)b1)[q];
    float p0 = 0.f, p1 = 0.f, p2 = 0.f, p3 = 0.f;
    for (int n = grp; n < NN; n += NGRP) {
        const int beg = row_start[n], end = row_end[n];
        float a0 = 0.f, a1 = 0.f, a2 = 0.f, a3 = 0.f;
        int i = beg + e;
        for (; i + 4 < end; i += 8) {  // 2 rows per slot in flight
            int s0 = csr[i];
            int s1 = csr[i + 4];
            const float4 v0 = *(const float4*)(hs + (size_t)s0 * 16 + q * 4);
            const float4 v1 = *(const float4*)(hs + (size_t)s1 * 16 + q * 4);
            a0 += v0.x + v1.x;
            a1 += v0.y + v1.y;
            a2 += v0.z + v1.z;
            a3 += v0.w + v1.w;
        }
        if (i < end) {
            const float4 v = *(const float4*)(hs + (size_t)csr[i] * 16 + q * 4);
            a0 += v.x; a1 += v.y; a2 += v.z; a3 += v.w;
        }
        // reduce across 4 edge slots (lane bits 2,3)
        a0 += __shfl_xor(a0, 4, 64); a1 += __shfl_xor(a1, 4, 64);
        a2 += __shfl_xor(a2, 4, 64); a3 += __shfl_xor(a3, 4, 64);
        a0 += __shfl_xor(a0, 8, 64); a1 += __shfl_xor(a1, 8, 64);
        a2 += __shfl_xor(a2, 8, 64); a3 += __shfl_xor(a3, 8, 64);
        if (e == 0) {
            const float dn = dinv[n];
            const float4 hv = *(const float4*)(hs + (size_t)n * 16 + q * 4);
            const float ww = dn * (cacc[n] + dn);
            p0 += ww * fmaxf(dn * (a0 + hv.x) + b1v.x, 0.f);
            p1 += ww * fmaxf(dn * (a1 + hv.y) + b1v.y, 0.f);
            p2 += ww * fmaxf(dn * (a2 + hv.z) + b1v.z, 0.f);
            p3 += ww * fmaxf(dn * (a3 + hv.w) + b1v.w, 0.f);
        }
    }
    __shared__ float red[16][16];
    if (e == 0) {
        float* r = &red[wid * 4 + g2][q * 4];
        r[0] = p0; r[1] = p1; r[2] = p2; r[3] = p3;
    }
    __syncthreads();
    if (tid < 16) {
        float s = 0.0f;
#pragma unroll
        for (int r = 0; r < 16; ++r) s += red[r][tid];
        pblock[blockIdx.x * 16 + tid] = s;
    }
    // ---- last-block finalize ----
    __shared__ int lastflag;
    __syncthreads();
    if (tid == 0) {
        __threadfence();
        lastflag = (atomicAdd(done, 1) == GBLK - 1) ? 1 : 0;
    }
    __syncthreads();
    if (!lastflag) return;
    __threadfence();
    __shared__ float red2[16][16];
    {
        const int c = tid & 15;
        const int r = tid >> 4;
        float s = 0.0f;
        for (int i = r; i < GBLK; i += 16) s += pblock[i * 16 + c];
        red2[r][c] = s;
    }
    __syncthreads();
    __shared__ float tv[16];
    __shared__ float vals[16];
    if (tid < 16) {
        float tot = 0.0f;
#pragma unroll
        for (int i = 0; i < 16; ++i) tot += red2[i][tid];
        tv[tid] = tot;
    }
    __syncthreads();
    if (tid < 16) {
        float acc = 0.0f;
#pragma unroll
        for (int cc = 0; cc < 16; ++cc) acc += tv[cc] * W2[cc * 16 + tid];
        vals[tid] = acc * (1.0f / NN) + b2[tid];
    }
    __syncthreads();
    if (tid < 16) {
        float m = -INFINITY;
        for (int i = 0; i < 16; ++i) m = fmaxf(m, vals[i]);
        float sum = 0.0f;
        for (int i = 0; i < 16; ++i) sum += expf(vals[i] - m);
        out[tid] = expf(vals[tid] - m) / sum;
    }
}

extern "C" void kernel_launch(void* const* d_in, const int* in_sizes, int n_in,
                              void* d_out, int out_size, void* d_ws, size_t ws_size,
                              hipStream_t stream) {
    const float* x = (const float*)d_in[0];
    const int* edge = (const int*)d_in[1];
    const float* W1 = (const float*)d_in[2];
    const float* b1 = (const float*)d_in[3];
    const float* W2 = (const float*)d_in[4];
    const float* b2 = (const float*)d_in[5];
    const int* src = edge;
    const int* dst = edge + NE;

    // workspace layout (int units); hs 16B-aligned
    char* ws = (char*)d_ws;
    int* gcount = (int*)ws;                            // NB2 + done -> pad 1600
    unsigned* packed = (unsigned*)(gcount + 1600);     // NB2*BCAP = 12812288
    int* row_start = (int*)(packed + (size_t)NB2 * BCAP);  // NN
    int* row_end = row_start + NN;                     // NN
    float* dinv = (float*)(row_end + NN);              // NN
    float* hs = dinv + NN;                             // NN*16 (16B aligned)
    float* cacc = hs + (size_t)NN * 16;                // NN
    float* pblock = cacc + NN;                         // GBLK*16
    int* done = gcount + DONE_IDX;

    float* out = (float*)d_out;

    k_zero<<<1, 1024, 0, stream>>>(gcount);
    k_histplace<<<NCH, 256, 0, stream>>>(src, dst, gcount, packed);
    k_bsort<<<NB, 256, 0, stream>>>(packed, gcount, row_start, row_end, dinv);
    k_gemm1csum<<<NGB + NB, 256, 0, stream>>>(x, W1, dinv, hs, packed, gcount, cacc);
    k_gather<<<GBLK, 256, 0, stream>>>(hs, dinv, row_start, row_end, packed, cacc,
                                       b1, pblock, done, W2, b2, out);
}

// Round 7
// 547.069 us; speedup vs baseline: 1.0348x; 1.0348x over previous
//
#include <hip/hip_runtime.h>
#include <hip/hip_bf16.h>
#include <hip/hip_fp16.h>
#include <math.h>

#define NN 100000
#define NE 3200000
#define NF 512
#define NTILE 6250    // NN/16 exactly
#define NB 782        // 128-node buckets per key (782*128 = 100096 >= NN)
#define NB2 1564      // both keys
#define NCH 1024      // edge chunks (4 blocks/CU for latency hiding)
#define CHUNK 3125    // NE/NCH exactly
#define BCAP 8192     // fixed bucket capacity (mean 4093, ~64 sigma margin)
#define NGB 1563      // gemm1 blocks = ceil(NTILE/4)
#define GBLK 2048     // gather blocks
#define NGRP (GBLK * 16)  // gather 16-lane groups (4 per wave)
#define DONE_IDX 1564     // 'done' counter lives in gcount pad

typedef __attribute__((ext_vector_type(8))) short short8;
typedef __attribute__((ext_vector_type(4))) float f32x4;

__device__ inline unsigned bf16_rne(float f) {
    unsigned u = __builtin_bit_cast(unsigned, f);
    return (u + 0x7FFFu + ((u >> 16) & 1u)) >> 16;
}
__device__ inline float bf16_back(unsigned h) {
    return __builtin_bit_cast(float, h << 16);
}
__device__ inline float2 h2f2(unsigned u) {
    __half2 h = __builtin_bit_cast(__half2, u);
    return __half22float2(h);
}

// ---------------- zero reservation counters + done flag ----------------
__global__ __launch_bounds__(1024) void k_zero(int* __restrict__ gcount) {
    for (int i = threadIdx.x; i < 1600; i += 1024) gcount[i] = 0;
}

// -------- fused hist + place, fixed-capacity buckets (no global scan) ---------
// bucket k segment: packed[k*BCAP .. k*BCAP + gcount[k])
// k = dst>>7 for dst-key copy (payload ((dst&127)<<17)|src)
// k = NB + (src>>7) for src-key copy (payload ((src&127)<<17)|dst)
__global__ __launch_bounds__(256) void k_histplace(const int* __restrict__ src,
                                                   const int* __restrict__ dst,
                                                   int* __restrict__ gcount,
                                                   unsigned* __restrict__ packed) {
    __shared__ int lcnt[NB2];
    __shared__ int sbase[NB2];
    for (int i = threadIdx.x; i < NB2; i += 256) lcnt[i] = 0;
    __syncthreads();
    const int e0 = blockIdx.x * CHUNK;
    // pass 1: count
    for (int i = threadIdx.x; i < CHUNK; i += 256) {
        atomicAdd(&lcnt[dst[e0 + i] >> 7], 1);
        atomicAdd(&lcnt[NB + (src[e0 + i] >> 7)], 1);
    }
    __syncthreads();
    // reserve: rotate start bucket per block to spread same-address contention
    const int rot = (blockIdx.x * 61) % NB2;
    for (int k = threadIdx.x; k < NB2; k += 256) {
        int b = k + rot;
        if (b >= NB2) b -= NB2;
        int c = lcnt[b];
        sbase[b] = b * BCAP + (c ? atomicAdd(&gcount[b], c) : 0);
        lcnt[b] = 0;  // reuse as cursor
    }
    __syncthreads();
    // pass 2: place (chunk is L2-hot from pass 1)
    for (int i = threadIdx.x; i < CHUNK; i += 256) {
        int d = dst[e0 + i];
        int s = src[e0 + i];
        int bd = d >> 7;
        int pd = atomicAdd(&lcnt[bd], 1);
        packed[sbase[bd] + pd] = ((unsigned)(d & 127) << 17) | (unsigned)s;
        int bs = NB + (s >> 7);
        int ps = atomicAdd(&lcnt[bs], 1);
        packed[sbase[bs] + ps] = ((unsigned)(s & 127) << 17) | (unsigned)d;
    }
}

// ---------------- per-bucket counting sort -> node CSR (+dinv), in place ------
// writes row_start[n], row_end[n] (no sentinel needed), dinv[n]
__global__ __launch_bounds__(256) void k_bsort(unsigned* __restrict__ packed,
                                               const int* __restrict__ gcount,
                                               int* __restrict__ row_start,
                                               int* __restrict__ row_end,
                                               float* __restrict__ dinv) {
    __shared__ unsigned stage[BCAP];
    __shared__ int cnt[128];
    __shared__ int t0[128], t1[128];
    const int tid = threadIdx.x;
    const int b = blockIdx.x;
    const int beg = b * BCAP;
    const int sz = gcount[b];
    if (tid < 128) cnt[tid] = 0;
    __syncthreads();
    for (int i = tid; i < sz; i += 256) {
        unsigned p = packed[beg + i];
        if (i < BCAP) stage[i] = p;
        atomicAdd(&cnt[p >> 17], 1);
    }
    __syncthreads();
    // inclusive Hillis-Steele scan over 128 counts
    if (tid < 128) t0[tid] = cnt[tid];
    __syncthreads();
    int pp = 0;
    for (int off = 1; off < 128; off <<= 1) {
        if (tid < 128) {
            int t = (pp ? t1[tid] : t0[tid]);
            if (tid >= off) t += (pp ? t1[tid - off] : t0[tid - off]);
            if (pp) t0[tid] = t; else t1[tid] = t;
        }
        __syncthreads();
        pp = 1 - pp;
    }
    if (tid < 128) {
        int incl = pp ? t1[tid] : t0[tid];
        int excl = incl - cnt[tid];
        int n = b * 128 + tid;
        if (n < NN) {
            row_start[n] = beg + excl;
            row_end[n] = beg + incl;
            dinv[n] = rsqrtf((float)cnt[tid] + 1.0f);
        }
        cnt[tid] = excl;  // reuse as cursor
    }
    __syncthreads();
    for (int i = tid; i < sz; i += 256) {
        unsigned p = (i < BCAP) ? stage[i] : packed[beg + i];
        int k = p >> 17;
        int pos = atomicAdd(&cnt[k], 1);
        packed[beg + pos] = p & 0x1FFFFu;
    }
}

// ---------------- GEMM1 (MFMA bf16 hi/lo) + csum, disjoint block ranges -------
// blocks [0,NGB): hs[n][c] = fp16(dinv[n]*(x@W1)[n][c])  (3.2MB -> L2-resident)
// blocks [NGB,NGB+NB): cacc[s] = sum_{edges s->d} dinv[d]  (latency-bound;
//   co-runs with the HBM-bound gemm -> complementary pipes)
__global__ __launch_bounds__(256) void k_gemm1csum(
    const float* __restrict__ x, const float* __restrict__ W1,
    const float* __restrict__ dinv, __half* __restrict__ hs,
    const unsigned* __restrict__ packed, const int* __restrict__ gcount,
    float* __restrict__ cacc) {
    if (blockIdx.x >= NGB) {
        // ---- csum branch ----
        __shared__ float sums[128];
        const int tid = threadIdx.x;
        const int b = blockIdx.x - NGB;
        if (tid < 128) sums[tid] = 0.0f;
        __syncthreads();
        const int beg = (NB + b) * BCAP;
        const int sz = gcount[NB + b];
        for (int i = tid; i < sz; i += 256) {
            unsigned p = packed[beg + i];
            atomicAdd(&sums[p >> 17], dinv[p & 0x1FFFFu]);
        }
        __syncthreads();
        const int n = b * 128 + tid;
        if (tid < 128 && n < NN) cacc[n] = sums[tid];
        return;
    }
    // ---- gemm branch ----
    __shared__ short8 Bh[1024];  // idx = (kk*4+q)*16 + c
    __shared__ short8 Bl[1024];

    const int t = threadIdx.x;
    {   // stage W: thread (c,q,kk0) handles kk = kk0*4+i
        const int c = t & 15, q = (t >> 4) & 3, kk0 = t >> 6;
        for (int i = 0; i < 4; ++i) {
            const int kk = kk0 * 4 + i;
            short8 hi, lo;
#pragma unroll
            for (int j = 0; j < 8; ++j) {
                float w = W1[(kk * 32 + q * 8 + j) * 16 + c];
                unsigned h = bf16_rne(w);
                float back = bf16_back(h);
                unsigned l = bf16_rne(w - back);
                hi[j] = (short)h;
                lo[j] = (short)l;
            }
            Bh[(kk * 4 + q) * 16 + c] = hi;
            Bl[(kk * 4 + q) * 16 + c] = lo;
        }
    }
    __syncthreads();

    const int lane = t & 63;
    const int wave = blockIdx.x * 4 + (t >> 6);
    if (wave >= NTILE) return;
    const int nb = wave * 16;
    const int m = lane & 15;  // A row within tile AND B/C col (channel)
    const int q = lane >> 4;

    const float4* xrow = (const float4*)(x + (size_t)(nb + m) * NF + q * 8);
    float4 xr[32];
#pragma unroll
    for (int kk = 0; kk < 16; ++kk) {
        xr[2 * kk] = xrow[kk * 8];
        xr[2 * kk + 1] = xrow[kk * 8 + 1];
    }

    f32x4 acc = {0.f, 0.f, 0.f, 0.f};
#pragma unroll
    for (int kk = 0; kk < 16; ++kk) {
        float f[8] = {xr[2 * kk].x,     xr[2 * kk].y,     xr[2 * kk].z,
                      xr[2 * kk].w,     xr[2 * kk + 1].x, xr[2 * kk + 1].y,
                      xr[2 * kk + 1].z, xr[2 * kk + 1].w};
        short8 ah, al;
#pragma unroll
        for (int j = 0; j < 8; ++j) {
            unsigned h = bf16_rne(f[j]);
            ah[j] = (short)h;
            al[j] = (short)bf16_rne(f[j] - bf16_back(h));
        }
        short8 bh = Bh[(kk * 4 + q) * 16 + m];
        short8 bl = Bl[(kk * 4 + q) * 16 + m];
        acc = __builtin_amdgcn_mfma_f32_16x16x32_bf16(ah, bh, acc, 0, 0, 0);
        acc = __builtin_amdgcn_mfma_f32_16x16x32_bf16(ah, bl, acc, 0, 0, 0);
        acc = __builtin_amdgcn_mfma_f32_16x16x32_bf16(al, bh, acc, 0, 0, 0);
    }

    // C/D: col=lane&15, row=q*4+reg
#pragma unroll
    for (int r = 0; r < 4; ++r) {
        const int n = nb + q * 4 + r;
        hs[n * 16 + m] = __float2half(dinv[n] * acc[r]);
    }
}

// -------- gather + fused layer-2 finalize/pool + last-block softmax -----------
// 16-lane group per node (4 nodes/wave): slot e=(lane>>2)&3, quad q=lane&3.
// hs is fp16 [NN][16] = 3.2MB -> per-XCD-L2 resident; each lane loads 8B.
// per node: a1 = dinv[n]*(sum_{s in N(n)} hs[s] + hs[n]);
//   pooled partial += w[n]*relu(a1+b1), w[n] = dinv[n]*(cacc[n]+dinv[n]).
// Block partial -> pblock; last block reduces + (t@W2)/N + b2 + softmax -> out.
__global__ __launch_bounds__(256) void k_gather(
    const __half* __restrict__ hs, const float* __restrict__ dinv,
    const int* __restrict__ row_start, const int* __restrict__ row_end,
    const unsigned* __restrict__ packed, const float* __restrict__ cacc,
    const float* __restrict__ b1, float* __restrict__ pblock,
    int* __restrict__ done, const float* __restrict__ W2,
    const float* __restrict__ b2, float* __restrict__ out) {
    const int* csr = (const int*)packed;
    const int tid = threadIdx.x;
    const int lane = tid & 63;
    const int wid = tid >> 6;
    const int g2 = lane >> 4;       // group within wave 0..3
    const int e = (lane >> 2) & 3;  // edge slot 0..3
    const int q = lane & 3;         // channel quad 0..3
    const int grp = blockIdx.x * 16 + wid * 4 + g2;
    const float4 b1v = ((const float4*)b1)[q];
    float p0 = 0.f, p1 = 0.f, p2 = 0.f, p3 = 0.f;
    for (int n = grp; n < NN; n += NGRP) {
        const int beg = row_start[n], end = row_end[n];
        float a0 = 0.f, a1 = 0.f, a2 = 0.f, a3 = 0.f;
        int i = beg + e;
        for (; i + 4 < end; i += 8) {  // 2 rows per slot in flight
            int s0 = csr[i];
            int s1 = csr[i + 4];
            const uint2 u0 = *(const uint2*)(hs + (size_t)s0 * 16 + q * 4);
            const uint2 u1 = *(const uint2*)(hs + (size_t)s1 * 16 + q * 4);
            const float2 x0 = h2f2(u0.x), y0 = h2f2(u0.y);
            const float2 x1 = h2f2(u1.x), y1 = h2f2(u1.y);
            a0 += x0.x + x1.x;
            a1 += x0.y + x1.y;
            a2 += y0.x + y1.x;
            a3 += y0.y + y1.y;
        }
        if (i < end) {
            const uint2 u0 = *(const uint2*)(hs + (size_t)csr[i] * 16 + q * 4);
            const float2 x0 = h2f2(u0.x), y0 = h2f2(u0.y);
            a0 += x0.x; a1 += x0.y; a2 += y0.x; a3 += y0.y;
        }
        // reduce across 4 edge slots (lane bits 2,3)
        a0 += __shfl_xor(a0, 4, 64); a1 += __shfl_xor(a1, 4, 64);
        a2 += __shfl_xor(a2, 4, 64); a3 += __shfl_xor(a3, 4, 64);
        a0 += __shfl_xor(a0, 8, 64); a1 += __shfl_xor(a1, 8, 64);
        a2 += __shfl_xor(a2, 8, 64); a3 += __shfl_xor(a3, 8, 64);
        if (e == 0) {
            const float dn = dinv[n];
            const uint2 uh = *(const uint2*)(hs + (size_t)n * 16 + q * 4);
            const float2 h01 = h2f2(uh.x), h23 = h2f2(uh.y);
            const float ww = dn * (cacc[n] + dn);
            p0 += ww * fmaxf(dn * (a0 + h01.x) + b1v.x, 0.f);
            p1 += ww * fmaxf(dn * (a1 + h01.y) + b1v.y, 0.f);
            p2 += ww * fmaxf(dn * (a2 + h23.x) + b1v.z, 0.f);
            p3 += ww * fmaxf(dn * (a3 + h23.y) + b1v.w, 0.f);
        }
    }
    __shared__ float red[16][16];
    if (e == 0) {
        float* r = &red[wid * 4 + g2][q * 4];
        r[0] = p0; r[1] = p1; r[2] = p2; r[3] = p3;
    }
    __syncthreads();
    if (tid < 16) {
        float s = 0.0f;
#pragma unroll
        for (int r = 0; r < 16; ++r) s += red[r][tid];
        pblock[blockIdx.x * 16 + tid] = s;
    }
    // ---- last-block finalize ----
    __shared__ int lastflag;
    __syncthreads();
    if (tid == 0) {
        __threadfence();
        lastflag = (atomicAdd(done, 1) == GBLK - 1) ? 1 : 0;
    }
    __syncthreads();
    if (!lastflag) return;
    __threadfence();
    __shared__ float red2[16][16];
    {
        const int c = tid & 15;
        const int r = tid >> 4;
        float s = 0.0f;
        for (int i = r; i < GBLK; i += 16) s += pblock[i * 16 + c];
        red2[r][c] = s;
    }
    __syncthreads();
    __shared__ float tv[16];
    __shared__ float vals[16];
    if (tid < 16) {
        float tot = 0.0f;
#pragma unroll
        for (int i = 0; i < 16; ++i) tot += red2[i][tid];
        tv[tid] = tot;
    }
    __syncthreads();
    if (tid < 16) {
        float acc = 0.0f;
#pragma unroll
        for (int cc = 0; cc < 16; ++cc) acc += tv[cc] * W2[cc * 16 + tid];
        vals[tid] = acc * (1.0f / NN) + b2[tid];
    }
    __syncthreads();
    if (tid < 16) {
        float m = -INFINITY;
        for (int i = 0; i < 16; ++i) m = fmaxf(m, vals[i]);
        float sum = 0.0f;
        for (int i = 0; i < 16; ++i) sum += expf(vals[i] - m);
        out[tid] = expf(vals[tid] - m) / sum;
    }
}

extern "C" void kernel_launch(void* const* d_in, const int* in_sizes, int n_in,
                              void* d_out, int out_size, void* d_ws, size_t ws_size,
                              hipStream_t stream) {
    const float* x = (const float*)d_in[0];
    const int* edge = (const int*)d_in[1];
    const float* W1 = (const float*)d_in[2];
    const float* b1 = (const float*)d_in[3];
    const float* W2 = (const float*)d_in[4];
    const float* b2 = (const float*)d_in[5];
    const int* src = edge;
    const int* dst = edge + NE;

    // workspace layout (int units); hs 8B-aligned fp16
    char* ws = (char*)d_ws;
    int* gcount = (int*)ws;                            // NB2 + done -> pad 1600
    unsigned* packed = (unsigned*)(gcount + 1600);     // NB2*BCAP = 12812288
    int* row_start = (int*)(packed + (size_t)NB2 * BCAP);  // NN
    int* row_end = row_start + NN;                     // NN
    float* dinv = (float*)(row_end + NN);              // NN
    __half* hs = (__half*)(dinv + NN);                 // NN*16 fp16 (3.2MB)
    float* cacc = (float*)(hs + (size_t)NN * 16);      // NN
    float* pblock = cacc + NN;                         // GBLK*16
    int* done = gcount + DONE_IDX;

    float* out = (float*)d_out;

    k_zero<<<1, 1024, 0, stream>>>(gcount);
    k_histplace<<<NCH, 256, 0, stream>>>(src, dst, gcount, packed);
    k_bsort<<<NB, 256, 0, stream>>>(packed, gcount, row_start, row_end, dinv);
    k_gemm1csum<<<NGB + NB, 256, 0, stream>>>(x, W1, dinv, hs, packed, gcount, cacc);
    k_gather<<<GBLK, 256, 0, stream>>>(hs, dinv, row_start, row_end, packed, cacc,
                                       b1, pblock, done, W2, b2, out);
}